// Round 3
// baseline (365.145 us; speedup 1.0000x reference)
//
#include <hip/hip_runtime.h>

// SoftDecisionTree fused pipeline for MI355X (gfx950).
// Inputs: x[16384,2048] f32, y[16384,1000] f32 one-hot, W[255,2048] f32,
//         b[255] f32, beta[255] f32, leaf_params[256,1000] f32
// Output: [loss(1) | output(16384*1000)] f32
//
// Round 3 gemm: BM=64, BN=256 (full N -> x read ONCE), K split 4 (grid 256x1x4
// = 1024 blocks = 4/CU for cross-block latency hiding). Wave tile 64x64:
// 16 MFMA + 8 ds_read_b128 per BK=32 step (m97 density). B staged via
// global_load_lds with XOR seg-swizzle (write & read sides) -> conflict-free
// b128 reads. A fp32->bf16 converted in-kernel (padded stride-40 LDS).

typedef __attribute__((ext_vector_type(8))) short short8;
typedef __attribute__((ext_vector_type(4))) float f32x4;

#define DIM 2048
#define NCLS 1000
#define NINNER 255
#define NPAD 256
#define PSTRIDE (16384ull * NPAD)  // floats per K-partial plane

__device__ __forceinline__ unsigned cvt2bf(float a, float b) {
  // round-half-up fp32 -> bf16, packed pair
  return ((__float_as_uint(a) + 0x8000u) >> 16) | ((__float_as_uint(b) + 0x8000u) & 0xFFFF0000u);
}

__device__ __forceinline__ void async_copy16(const unsigned short* gsrc, unsigned short* ldst) {
  __builtin_amdgcn_global_load_lds(
      (const __attribute__((address_space(1))) unsigned int*)(gsrc),
      (__attribute__((address_space(3))) unsigned int*)(ldst), 16, 0, 0);
}

__global__ __launch_bounds__(256) void prep_w(const float* __restrict__ W,
                                              const float* __restrict__ b,
                                              const float* __restrict__ beta,
                                              unsigned short* __restrict__ Wb,
                                              float* __restrict__ bp,
                                              float* __restrict__ betap) {
  int i = blockIdx.x * 256 + threadIdx.x;  // over 256*2048
  int n = i >> 11;
  float v = (n < NINNER) ? W[i] : 0.f;     // rows 0..254 are W; row 255 zero pad
  Wb[i] = (unsigned short)((__float_as_uint(v) + 0x8000u) >> 16);
  if (i < NPAD) {
    bp[i] = (i < NINNER) ? b[i] : 0.f;
    betap[i] = (i < NINNER) ? beta[i] : 0.f;
  }
}

__global__ __launch_bounds__(256) void leaf_softmax(const float* __restrict__ leaf,
                                                    float* __restrict__ logQT,
                                                    float* __restrict__ Q) {
  int l = blockIdx.x, t = threadIdx.x;
  const float* row = leaf + (size_t)l * NCLS;
  __shared__ float red[256];
  float mx = -3.4e38f;
  for (int j = t; j < NCLS; j += 256) mx = fmaxf(mx, row[j]);
  red[t] = mx; __syncthreads();
  for (int s = 128; s; s >>= 1) { if (t < s) red[t] = fmaxf(red[t], red[t + s]); __syncthreads(); }
  mx = red[0]; __syncthreads();
  float sm = 0.f;
  for (int j = t; j < NCLS; j += 256) sm += __expf(row[j] - mx);
  red[t] = sm; __syncthreads();
  for (int s = 128; s; s >>= 1) { if (t < s) red[t] += red[t + s]; __syncthreads(); }
  float lse = mx + __logf(red[0]);
  for (int j = t; j < NCLS; j += 256) {
    float lg = row[j] - lse;
    logQT[(size_t)j * NPAD + l] = lg;      // transposed: [class][leaf]
    Q[(size_t)l * NCLS + j] = __expf(lg);
  }
}

__global__ __launch_bounds__(256) void find_targets(const float* __restrict__ y,
                                                    int* __restrict__ tgt) {
  int wv = threadIdx.x >> 6, lane = threadIdx.x & 63;
  int r = blockIdx.x * 4 + wv;
  const float4* yr = (const float4*)(y + (size_t)r * NCLS);
  int found = 0x7fffffff;
#pragma unroll
  for (int i = 0; i < 4; ++i) {
    int j4 = i * 64 + lane;
    if (j4 < 250) {
      float4 v = yr[j4];
      if (v.x > 0.5f) found = min(found, 4 * j4 + 0);
      if (v.y > 0.5f) found = min(found, 4 * j4 + 1);
      if (v.z > 0.5f) found = min(found, 4 * j4 + 2);
      if (v.w > 0.5f) found = min(found, 4 * j4 + 3);
    }
  }
  for (int off = 32; off; off >>= 1) found = min(found, __shfl_down(found, off));
  if (lane == 0) tgt[r] = found;
}

// GEMM: BM=64, BN=256, BK=32, K split in 4 (blockIdx.z). Grid 256x1x4 = 1024
// blocks (4/CU). 4 waves split N; each wave computes 64x64 via 4x4 mfma tiles.
// B LDS layout: row n (0..255) occupies 64 B; within a row the four 16-B segs
// are XOR-swizzled by mask(n%16) = (n + n/4) & 3 on both write (global fetch
// address permutation under global_load_lds's lane*16 placement) and read.
__global__ __launch_bounds__(256, 4) void gemm_xwT(const float* __restrict__ x,
                                                   const unsigned short* __restrict__ Wb,
                                                   float* __restrict__ P) {
  __shared__ __align__(16) unsigned short As[64 * 40];   // stride 40 (80 B, 16B-aligned, 2-way free)
  __shared__ __align__(16) unsigned short Bs[256 * 32];  // swizzled, conflict-free

  int tid = threadIdx.x;
  int lane = tid & 63, wave = tid >> 6;
  int m_base = blockIdx.x * 64;
  int k_base = blockIdx.z * 512;
  float* Pz = P + (size_t)blockIdx.z * PSTRIDE;

  f32x4 acc[4][4] = {};

  // A staging: thread t loads 8 floats of row (t>>2), seg (t&3)
  int arow = tid >> 2, aseg = tid & 3;
  const float* aptr = x + (size_t)(m_base + arow) * DIM + k_base + aseg * 8;
  unsigned short* asd = &As[arow * 40 + aseg * 8];

  // B staging: wave w stages chunks w*4..w*4+3 (16 rows x 64 B each) via
  // global_load_lds. Lane l -> relative row rr=l>>2, physical seg sp=l&3,
  // fetches global seg sp ^ mask(rr).
  int rr = lane >> 2;
  int sg = (lane & 3) ^ ((rr + (rr >> 2)) & 3);
  const unsigned short* bg0 = Wb + (size_t)(wave * 64 + rr) * DIM + k_base + sg * 8;
  const unsigned short* bg1 = bg0 + 16 * DIM;
  const unsigned short* bg2 = bg0 + 32 * DIM;
  const unsigned short* bg3 = bg0 + 48 * DIM;
  unsigned short* bl0 = &Bs[(wave * 4 + 0) * 512];
  unsigned short* bl1 = &Bs[(wave * 4 + 1) * 512];
  unsigned short* bl2 = &Bs[(wave * 4 + 2) * 512];
  unsigned short* bl3 = &Bs[(wave * 4 + 3) * 512];

  int frow = lane & 15, q = lane >> 4;
  int bseg = (q ^ ((frow + (frow >> 2)) & 3)) * 8;  // swizzled seg (shorts)
  int wcol = wave * 64;

  for (int kt = 0; kt < 512; kt += 32) {
    float4 v0 = *(const float4*)(aptr + kt);
    float4 v1 = *(const float4*)(aptr + kt + 4);
    uint4 pk;
    pk.x = cvt2bf(v0.x, v0.y); pk.y = cvt2bf(v0.z, v0.w);
    pk.z = cvt2bf(v1.x, v1.y); pk.w = cvt2bf(v1.z, v1.w);
    __syncthreads();  // previous iteration's frag reads complete
    *(uint4*)asd = pk;
    async_copy16(bg0 + kt, bl0);
    async_copy16(bg1 + kt, bl1);
    async_copy16(bg2 + kt, bl2);
    async_copy16(bg3 + kt, bl3);
    __syncthreads();  // staging visible (incl. async B)
    short8 a[4];
#pragma unroll
    for (int mt = 0; mt < 4; ++mt)
      a[mt] = *(const short8*)&As[(mt * 16 + frow) * 40 + q * 8];
#pragma unroll
    for (int nt = 0; nt < 4; ++nt) {
      short8 bb = *(const short8*)&Bs[(wcol + nt * 16 + frow) * 32 + bseg];
#pragma unroll
      for (int mt = 0; mt < 4; ++mt)
        acc[mt][nt] = __builtin_amdgcn_mfma_f32_16x16x32_bf16(a[mt], bb, acc[mt][nt], 0, 0, 0);
    }
  }
  // C/D layout: col = lane&15 (n), row = (lane>>4)*4 + reg (m). Raw fp32 partials.
#pragma unroll
  for (int mt = 0; mt < 4; ++mt) {
#pragma unroll
    for (int rg = 0; rg < 4; ++rg) {
      float* dst = Pz + (size_t)(m_base + mt * 16 + q * 4 + rg) * NPAD + wcol + frow;
#pragma unroll
      for (int nt = 0; nt < 4; ++nt) dst[nt * 16] = acc[mt][nt][rg];
    }
  }
}

// 1024 blocks x 4 waves x 4 rows. Fused epilogue: p = sigmoid(beta*(sum P + b))
// staged per-wave in LDS, then tree math, node sums S0/S1 (LDS atomics),
// logQT float4 dot, argmax leaf.
__global__ __launch_bounds__(256) void tree_walk(const float* __restrict__ P,
                                                 const float* __restrict__ bp,
                                                 const float* __restrict__ betap,
                                                 const float* __restrict__ logQT,
                                                 const int* __restrict__ tgt,
                                                 float* __restrict__ acc,  // [S0:127][S1:127][dot:1]
                                                 int* __restrict__ best) {
  __shared__ float ws[4][256];
  __shared__ float s0s[127], s1s[127];
  __shared__ float sdot;
  int tid = threadIdx.x;
  int lane = tid & 63, wv = tid >> 6;
  if (tid < 127) { s0s[tid] = 0.f; s1s[tid] = 0.f; }
  if (tid == 255) sdot = 0.f;
  __syncthreads();
  float4 bb = *(const float4*)(bp + lane * 4);
  float4 be = *(const float4*)(betap + lane * 4);
  float* wsp = ws[wv];
  float wdot = 0.f;
  for (int it = 0; it < 4; ++it) {
    int r = blockIdx.x * 16 + wv * 4 + it;
    const float* pr = P + (size_t)r * NPAD + lane * 4;
    float4 u0 = *(const float4*)(pr);
    float4 u1 = *(const float4*)(pr + PSTRIDE);
    float4 u2 = *(const float4*)(pr + 2 * PSTRIDE);
    float4 u3 = *(const float4*)(pr + 3 * PSTRIDE);
    float4 pz;
    pz.x = 1.f / (1.f + __expf(-be.x * (u0.x + u1.x + u2.x + u3.x + bb.x)));
    pz.y = 1.f / (1.f + __expf(-be.y * (u0.y + u1.y + u2.y + u3.y + bb.y)));
    pz.z = 1.f / (1.f + __expf(-be.z * (u0.z + u1.z + u2.z + u3.z + bb.z)));
    pz.w = 1.f / (1.f + __expf(-be.w * (u0.w + u1.w + u2.w + u3.w + bb.w)));
    *(float4*)(wsp + lane * 4) = pz;
    __asm__ volatile("" ::: "memory");  // keep LDS write before cross-lane LDS reads
    int tg = tgt[r];
    float pp = 1.f;  // path product into current depth
#pragma unroll
    for (int d = 1; d <= 6; ++d) {
      int idx = (1 << (d - 1)) - 1 + (lane >> (7 - d));
      float p = wsp[idx];
      if ((lane & ((1 << (7 - d)) - 1)) == 0) {  // first lane covering this node
        atomicAdd(&s0s[idx], pp);
        atomicAdd(&s1s[idx], p * pp);
      }
      pp *= ((lane >> (6 - d)) & 1) ? p : (1.f - p);
    }
    float p7 = wsp[63 + lane];
    atomicAdd(&s0s[63 + lane], pp);
    atomicAdd(&s1s[63 + lane], p7 * pp);
    float pL = pp * (1.f - p7), pR = pp * p7;
    float p8a = wsp[127 + 2 * lane], p8b = wsp[128 + 2 * lane];
    float lf0 = pL * (1.f - p8a), lf1 = pL * p8a;
    float lf2 = pR * (1.f - p8b), lf3 = pR * p8b;
    float4 lq = *(const float4*)(logQT + (size_t)tg * NPAD + lane * 4);
    wdot += lf0 * lq.x + lf1 * lq.y + lf2 * lq.z + lf3 * lq.w;
    float bv = lf0; int bi = 4 * lane;
    if (lf1 > bv) { bv = lf1; bi = 4 * lane + 1; }
    if (lf2 > bv) { bv = lf2; bi = 4 * lane + 2; }
    if (lf3 > bv) { bv = lf3; bi = 4 * lane + 3; }
    for (int off = 32; off; off >>= 1) {
      float ov = __shfl_down(bv, off);
      int oi = __shfl_down(bi, off);
      if (ov > bv || (ov == bv && oi < bi)) { bv = ov; bi = oi; }  // first-max tie-break
    }
    if (lane == 0) best[r] = bi;
  }
  for (int off = 32; off; off >>= 1) wdot += __shfl_down(wdot, off);
  if (lane == 0) atomicAdd(&sdot, wdot);
  __syncthreads();
  if (tid < 127) {
    atomicAdd(&acc[tid], s0s[tid]);
    atomicAdd(&acc[127 + tid], s1s[tid]);
  }
  if (tid == 255) atomicAdd(&acc[254], sdot);
}

__global__ __launch_bounds__(128) void finalize_loss(const float* __restrict__ acc,
                                                     float* __restrict__ out) {
  __shared__ float red[128];
  int t = threadIdx.x;
  float c = 0.f;
  if (t < 127) {
    float denom = acc[t];
    if (denom == 0.f) denom = 1e-6f;
    float alpha = acc[127 + t] / denom;
    alpha = fminf(fmaxf(alpha, 1e-6f), 1.f - 1e-6f);
    int d = 31 - __clz(t + 1) + 1;  // depth: idx 0 -> 1, idx 1..2 -> 2, ...
    float lm = 0.1f * exp2f(-(float)d);
    c = -lm * 0.5f * (logf(alpha) + log1pf(-alpha));
  }
  red[t] = c;
  __syncthreads();
  for (int s = 64; s; s >>= 1) { if (t < s) red[t] += red[t + s]; __syncthreads(); }
  if (t == 0) out[0] = -(acc[254] / 16384.f) + red[0];
}

__global__ __launch_bounds__(256) void gather_rows(const float* __restrict__ Q,
                                                   const int* __restrict__ best,
                                                   float* __restrict__ out) {
  int wv = threadIdx.x >> 6, lane = threadIdx.x & 63;
  int r = blockIdx.x * 4 + wv;
  const float* src = Q + (size_t)best[r] * NCLS;
  float* dst = out + 1 + (size_t)r * NCLS;  // rows start at global index 1+1000r
  if (lane < 3) dst[lane] = src[lane];
  if (lane == 0) dst[999] = src[999];
#pragma unroll
  for (int i = 0; i < 4; ++i) {
    int q = i * 64 + lane;
    if (q < 249) {
      int o = 3 + 4 * q;  // 16B-aligned in dst
      float4 v = make_float4(src[o], src[o + 1], src[o + 2], src[o + 3]);
      *(float4*)(dst + o) = v;
    }
  }
}

extern "C" void kernel_launch(void* const* d_in, const int* in_sizes, int n_in,
                              void* d_out, int out_size, void* d_ws, size_t ws_size,
                              hipStream_t stream) {
  const float* x = (const float*)d_in[0];
  const float* y = (const float*)d_in[1];
  const float* W = (const float*)d_in[2];
  const float* b = (const float*)d_in[3];
  const float* beta = (const float*)d_in[4];
  const float* leaf = (const float*)d_in[5];
  float* out = (float*)d_out;
  char* ws = (char*)d_ws;

  // ws layout (~70.3 MB)
  unsigned short* Wb = (unsigned short*)(ws + 0);        // 1048576
  float* bp    = (float*)(ws + 1048576);                 // 1024
  float* betap = (float*)(ws + 1049600);                 // 1024
  float* acc   = (float*)(ws + 1050624);                 // 1024 (255 used)
  int* tgt     = (int*)(ws + 1051648);                   // 65536
  int* best    = (int*)(ws + 1117184);                   // 65536
  float* logQT = (float*)(ws + 1182720);                 // 1000*256*4 = 1024000
  float* Q     = (float*)(ws + 2206720);                 // 1024000
  float* P     = (float*)(ws + 3230720);                 // 4 * 16384*256*4 = 67108864

  prep_w<<<2048, 256, 0, stream>>>(W, b, beta, Wb, bp, betap);
  leaf_softmax<<<256, 256, 0, stream>>>(leaf, logQT, Q);
  find_targets<<<4096, 256, 0, stream>>>(y, tgt);
  gemm_xwT<<<dim3(256, 1, 4), 256, 0, stream>>>(x, Wb, P);
  hipMemsetAsync(acc, 0, 256 * sizeof(float), stream);
  tree_walk<<<1024, 256, 0, stream>>>(P, bp, betap, logQT, tgt, acc, best);
  finalize_loss<<<1, 128, 0, stream>>>(acc, out);
  gather_rows<<<4096, 256, 0, stream>>>(Q, best, out);
}